// Round 5
// baseline (309.057 us; speedup 1.0000x reference)
//
#include <hip/hip_runtime.h>

// SSIM loss, streaming-row formulation (R5).
// input [32,3,384,384] --bilinear(align_corners)--> [512,512] vs target; 11x11 gaussian
// SSIM (VALID) -> mean over (96,502,502) -> loss = clip(1-mean,0,1).
//
// Per block: one plane x 32-output-row chunk, 256 threads x 2 cols (even/odd split).
// Per region row: stage (s,d,s^2,d^2) float4 per col into even/odd de-interleaved LDS
// (conflict-free b128), horizontal 11-tap conv from 12 b128 taps, vertical conv via
// 11-slot register ring (static indices; ring in VGPRs thanks to launch_bounds(256,2)).
// Global loads are 2 rows ahead (pipeline slots statically indexed by row parity).

constexpr int KS = 11;
constexpr int HI = 384, WI = 384, HO = 512, WO = 512;
constexpr int OUTD = 502;            // HO - KS + 1
constexpr int NPLANE = 96;
constexpr int CH_OUT = 32;           // output rows per chunk
constexpr int NCHUNK = 16;
constexpr float C1 = 1.0e-4f;
constexpr float C2 = 9.0e-4f;

// gaussian(sigma=1.5, ks=11), normalized
__device__ __constant__ float GW[KS] = {
    0.00102838f, 0.00759876f, 0.03600076f, 0.10936070f, 0.21300554f,
    0.26601172f, 0.21300554f, 0.10936070f, 0.03600076f, 0.00759876f, 0.00102838f};

__device__ __forceinline__ float4 f4fma(float w, float4 x, float4 a)
{
    a.x = fmaf(w, x.x, a.x); a.y = fmaf(w, x.y, a.y);
    a.z = fmaf(w, x.z, a.z); a.w = fmaf(w, x.w, a.w);
    return a;
}

__device__ __forceinline__ float ssim_term(float4 f)
{
    float S = f.x, D = f.y, P = f.z, M = f.w;
    float SS = S * S, DD = D * D;
    float mu12 = 0.25f * (SS - DD);            // mu1*mu2
    float musq = 0.5f  * (SS + DD);            // mu1^2 + mu2^2
    float s12  = 0.25f * (P - M) - mu12;       // sigma12
    float ssum = 0.5f  * (P + M) - musq;       // sigma1 + sigma2
    float num = fmaf(2.f, mu12, C1) * fmaf(2.f, s12, C2);
    float den = (musq + C1) * (ssum + C2);
    return __fdividef(num, den);
}

__global__ __launch_bounds__(256, 2)
void ssim_stream(const float* __restrict__ input, const float* __restrict__ target,
                 double* __restrict__ accum)
{
    // even cols (2t) and odd cols (2t+1), de-interleaved: tap reads are
    // stride-16B/lane ds_read_b128 -> conflict-free. 262 = 256 + 6 halo slots.
    __shared__ __align__(16) float4 chE[2][262];
    __shared__ __align__(16) float4 chO[2][262];
    __shared__ float wave_sums[4];

    const int tid   = threadIdx.x;
    const int chunk = blockIdx.x;
    const int plane = blockIdx.y;
    const int oyb   = chunk * CH_OUT;
    const int nout  = min(CH_OUT, OUTD - oyb);
    const int rows  = nout + KS - 1;          // <= 42

    const int c0 = 2 * tid;

    // x-geometry (align_corners): p = c*383/511, f32-exact decision
    float pA = (float)(c0 * (WI - 1)) / (float)(WO - 1);
    int   xA0 = (int)pA; float wxA = pA - (float)xA0;
    float pB = (float)((c0 + 1) * (WI - 1)) / (float)(WO - 1);
    int   xB0 = (int)pB; float wxB = pB - (float)xB0;
    const bool shift = (xB0 != xA0);          // xB0 == xA0 or xA0+1
    const int xs0 = xA0, xs1 = xA0 + 1, xs2 = min(xA0 + 2, WI - 1);

    const float* __restrict__ ip = input  + (size_t)plane * HI * WI;
    const float* __restrict__ tp = target + (size_t)plane * HO * WO;

    // vertical ring: slot = oy % 11; (S,D,P,M) per col
    float4 rA[11], rB[11];
    #pragma unroll
    for (int s = 0; s < 11; ++s) {
        rA[s] = make_float4(0.f, 0.f, 0.f, 0.f);
        rB[s] = make_float4(0.f, 0.f, 0.f, 0.f);
    }

    // 2-deep preload pipeline, slot = row & 1 (statically resolved after unroll)
    float u0[2], u1[2], u2[2], v0[2], v1[2], v2[2], wyp[2];
    float2 tg[2];
    auto PRELOAD = [&](int r, int sl) {
        int y = oyb + r;                       // <= 511
        float py = (float)(y * (HI - 1)) / (float)(HO - 1);
        int y0 = (int)py; wyp[sl] = py - (float)y0;
        int y1 = min(y0 + 1, HI - 1);
        const float* r0 = ip + y0 * WI;
        const float* r1 = ip + y1 * WI;
        u0[sl] = r0[xs0]; u1[sl] = r0[xs1]; u2[sl] = r0[xs2];
        v0[sl] = r1[xs0]; v1[sl] = r1[xs1]; v2[sl] = r1[xs2];
        tg[sl] = *(const float2*)&tp[y * WO + c0];
    };

    float lsum = 0.f;
    PRELOAD(0, 0);
    PRELOAD(1, 1);

    for (int t = 0; t < 2; ++t) {
        #pragma unroll
        for (int i = 0; i < 22; ++i) {
            const int r = t * 22 + i;
            if (r < rows) {                    // block-uniform branch
                const int p = i & 1;           // static after unroll
                // ---- stage: consume pipeline slot p
                float wy = wyp[p];
                float V0 = fmaf(wy, v0[p] - u0[p], u0[p]);
                float V1 = fmaf(wy, v1[p] - u1[p], u1[p]);
                float V2 = fmaf(wy, v2[p] - u2[p], u2[p]);
                float a0 = fmaf(wxA, V1 - V0, V0);
                float bL = shift ? V1 : V0;
                float bR = shift ? V2 : V1;
                float a1 = fmaf(wxB, bR - bL, bL);
                float2 tv = tg[p];
                float s0 = a0 + tv.x, d0 = a0 - tv.x;
                float s1 = a1 + tv.y, d1 = a1 - tv.y;
                chE[p][tid] = make_float4(s0, d0, s0 * s0, d0 * d0);
                chO[p][tid] = make_float4(s1, d1, s1 * s1, d1 * d1);
                // ---- issue loads for row r+2 into slot p (regs survive barrier)
                if (r + 2 < rows) PRELOAD(r + 2, p);
                __syncthreads();
                // ---- horizontal 11-tap conv for cols c0 (acc0) and c0+1 (acc1)
                // acc0 = sum_m GW[2m]E[m] (m0..5) + GW[2m+1]O[m] (m0..4)
                // acc1 = sum_m GW[2m]O[m] (m0..5) + GW[2m-1]E[m] (m1..5)
                float4 acc0 = make_float4(0.f, 0.f, 0.f, 0.f);
                float4 acc1 = make_float4(0.f, 0.f, 0.f, 0.f);
                #pragma unroll
                for (int m = 0; m < 6; ++m) {
                    float4 E = chE[p][tid + m];
                    float4 O = chO[p][tid + m];
                    float we = GW[2 * m];
                    acc0 = f4fma(we, E, acc0);
                    acc1 = f4fma(we, O, acc1);
                    if (m < 5) acc0 = f4fma(GW[2 * m + 1], O, acc0);
                    if (m >= 1) acc1 = f4fma(GW[2 * m - 1], E, acc1);
                }
                // ---- vertical ring scatter; r mod 11 == i mod 11 (22 ≡ 0 mod 11)
                const int im = i % 11;
                #pragma unroll
                for (int j = 0; j < 11; ++j) {
                    const int sl = (im - j + 11) % 11;
                    rA[sl] = f4fma(GW[j], acc0, rA[sl]);
                    rB[sl] = f4fma(GW[j], acc1, rB[sl]);
                }
                // ---- output row oy = r-10 completes in slot (im+1)%11
                const int sf = (im + 1) % 11;
                if (r >= 10) {
                    if (c0 < OUTD) {
                        lsum += ssim_term(rA[sf]);
                        if (c0 + 1 < OUTD) lsum += ssim_term(rB[sf]);
                    }
                }
                rA[sf] = make_float4(0.f, 0.f, 0.f, 0.f);
                rB[sf] = make_float4(0.f, 0.f, 0.f, 0.f);
            }
        }
    }

    // block reduction: wave64 shuffle + LDS across 4 waves, one f64 atomic
    #pragma unroll
    for (int off = 32; off > 0; off >>= 1) lsum += __shfl_down(lsum, off);
    int wave = tid >> 6, lane = tid & 63;
    if (lane == 0) wave_sums[wave] = lsum;
    __syncthreads();
    if (tid == 0) {
        float s = wave_sums[0] + wave_sums[1] + wave_sums[2] + wave_sums[3];
        atomicAdd(accum, (double)s);
    }
}

__global__ void ssim_finalize(const double* __restrict__ accum, float* __restrict__ out)
{
    if (threadIdx.x == 0 && blockIdx.x == 0) {
        double mean = accum[0] / ((double)NPLANE * OUTD * OUTD);
        double l = 1.0 - mean;
        if (l < 0.0) l = 0.0;
        if (l > 1.0) l = 1.0;
        out[0] = (float)l;
    }
}

extern "C" void kernel_launch(void* const* d_in, const int* in_sizes, int n_in,
                              void* d_out, int out_size, void* d_ws, size_t ws_size,
                              hipStream_t stream)
{
    const float* input  = (const float*)d_in[0];   // [32,3,384,384]
    const float* target = (const float*)d_in[1];   // [32,3,512,512]
    float* out = (float*)d_out;
    double* accum = (double*)d_ws;

    hipMemsetAsync(accum, 0, sizeof(double), stream);

    dim3 grid(NCHUNK, NPLANE);
    ssim_stream<<<grid, dim3(256), 0, stream>>>(input, target, accum);
    ssim_finalize<<<1, 64, 0, stream>>>(accum, out);
}

// Round 6
// 301.163 us; speedup vs baseline: 1.0262x; 1.0262x over previous
//
#include <hip/hip_runtime.h>

// SSIM loss, streaming-row, vertical-conv-first (R6).
// input [32,3,384,384] --bilinear(align_corners)--> [512,512] vs target; 11x11 gaussian
// SSIM (VALID) -> mean over (96,502,502) -> loss = clip(1-mean,0,1).
//
// Per block: one plane x 32-output-row chunk; 256 threads x 2 cols.
// Per region row: bilinear from 2-deep preload pipeline -> (s=a+b, d=a-b) into an
// 11-slot register ring of RAW inputs (44 VGPRs, static indices; no LDS, no barrier).
// When an output row completes (r>=10): vertical 11-tap conv of (s,d,s^2,d^2) from
// the ring, write float4 to even/odd de-interleaved LDS (conflict-free b128),
// ONE barrier, horizontal 11-tap conv, SSIM. LDS work on 32 of 42 rows only.
// launch_bounds(256,4) keeps the ring in real VGPRs (no AGPR round-trips).

constexpr int KS = 11;
constexpr int HI = 384, WI = 384, HO = 512, WO = 512;
constexpr int OUTD = 502;            // HO - KS + 1
constexpr int NPLANE = 96;
constexpr int CH_OUT = 32;
constexpr int NCHUNK = 16;
constexpr float C1 = 1.0e-4f;
constexpr float C2 = 9.0e-4f;

// gaussian(sigma=1.5, ks=11), normalized
__device__ __constant__ float GW[KS] = {
    0.00102838f, 0.00759876f, 0.03600076f, 0.10936070f, 0.21300554f,
    0.26601172f, 0.21300554f, 0.10936070f, 0.03600076f, 0.00759876f, 0.00102838f};

__device__ __forceinline__ float4 f4fma(float w, float4 x, float4 a)
{
    a.x = fmaf(w, x.x, a.x); a.y = fmaf(w, x.y, a.y);
    a.z = fmaf(w, x.z, a.z); a.w = fmaf(w, x.w, a.w);
    return a;
}

__device__ __forceinline__ float ssim_term(float4 f)
{
    float S = f.x, D = f.y, P = f.z, M = f.w;
    float SS = S * S, DD = D * D;
    float mu12 = 0.25f * (SS - DD);            // mu1*mu2
    float musq = 0.5f  * (SS + DD);            // mu1^2 + mu2^2
    float s12  = 0.25f * (P - M) - mu12;       // sigma12
    float ssum = 0.5f  * (P + M) - musq;       // sigma1 + sigma2
    float num = fmaf(2.f, mu12, C1) * fmaf(2.f, s12, C2);
    float den = (musq + C1) * (ssum + C2);
    return __fdividef(num, den);
}

__global__ __launch_bounds__(256, 4)
void ssim_stream(const float* __restrict__ input, const float* __restrict__ target,
                 double* __restrict__ accum)
{
    // vertical-conv outputs (S,D,P,M) for even cols (2t) / odd cols (2t+1),
    // double-buffered by output-row parity. Reads at [tid+0..5] -> 262 slots.
    __shared__ __align__(16) float4 hE[2][262];
    __shared__ __align__(16) float4 hO[2][262];
    __shared__ float wave_sums[4];

    const int tid   = threadIdx.x;
    const int chunk = blockIdx.x;
    const int plane = blockIdx.y;
    const int oyb   = chunk * CH_OUT;
    const int nout  = min(CH_OUT, OUTD - oyb);
    const int rows  = nout + KS - 1;          // <= 42

    const int c0 = 2 * tid;

    // x-geometry (align_corners): p = c*383/511 (f32-exact decision)
    float pA = (float)(c0 * (WI - 1)) / (float)(WO - 1);
    int   xA0 = (int)pA; float wxA = pA - (float)xA0;
    float pB = (float)((c0 + 1) * (WI - 1)) / (float)(WO - 1);
    int   xB0 = (int)pB; float wxB = pB - (float)xB0;
    const bool shift = (xB0 != xA0);
    const int xs0 = xA0, xs1 = min(xA0 + 1, WI - 1), xs2 = min(xA0 + 2, WI - 1);

    const float* __restrict__ ip = input  + (size_t)plane * HI * WI;
    const float* __restrict__ tp = target + (size_t)plane * HO * WO;

    // raw-input ring: slot = region_row % 11, (s0,d0,s1,d1)
    float4 q[11];

    // 2-deep preload pipeline, slot = row parity (static after unroll)
    float u0[2], u1[2], u2[2], v0[2], v1[2], v2[2], wyp[2];
    float2 tg[2];
    auto PRELOAD = [&](int r, int sl) {
        int y = oyb + r;                       // <= 511
        float py = (float)(y * (HI - 1)) / (float)(HO - 1);
        int y0 = (int)py; wyp[sl] = py - (float)y0;
        int y1 = min(y0 + 1, HI - 1);
        const float* r0 = ip + y0 * WI;
        const float* r1 = ip + y1 * WI;
        u0[sl] = r0[xs0]; u1[sl] = r0[xs1]; u2[sl] = r0[xs2];
        v0[sl] = r1[xs0]; v1[sl] = r1[xs1]; v2[sl] = r1[xs2];
        tg[sl] = *(const float2*)&tp[y * WO + c0];
    };

    float lsum = 0.f;
    PRELOAD(0, 0);
    PRELOAD(1, 1);

    for (int t = 0; t < 2; ++t) {
        #pragma unroll
        for (int i = 0; i < 22; ++i) {
            const int r = t * 22 + i;                 // region row
            if (r < rows) {                           // block-uniform
                const int p  = i & 1;                 // static
                const int im = i % 11;                // static; r%11 == im
                // ---- consume pipeline slot p: bilinear -> (s,d) -> ring
                float wy = wyp[p];
                float V0 = fmaf(wy, v0[p] - u0[p], u0[p]);
                float V1 = fmaf(wy, v1[p] - u1[p], u1[p]);
                float V2 = fmaf(wy, v2[p] - u2[p], u2[p]);
                float a0 = fmaf(wxA, V1 - V0, V0);
                float bL = shift ? V1 : V0;
                float bR = shift ? V2 : V1;
                float a1 = fmaf(wxB, bR - bL, bL);
                float2 tv = tg[p];
                q[im] = make_float4(a0 + tv.x, a0 - tv.x, a1 + tv.y, a1 - tv.y);
                // ---- issue loads for row r+2 into slot p (regs survive barrier)
                if (r + 2 < rows) PRELOAD(r + 2, p);
                // ---- output row oy = r-10 complete: vertical conv from ring
                if (r >= KS - 1) {
                    float4 accA = make_float4(0.f, 0.f, 0.f, 0.f);  // (S0,D0,S1,D1)
                    float4 accB = make_float4(0.f, 0.f, 0.f, 0.f);  // (P0,M0,P1,M1)
                    #pragma unroll
                    for (int j = 0; j < KS; ++j) {
                        const int sl = (im + 1 + j) % 11;           // static
                        float4 x = q[sl];
                        float4 x2 = make_float4(x.x * x.x, x.y * x.y,
                                                x.z * x.z, x.w * x.w);
                        float w = GW[j];
                        accA = f4fma(w, x,  accA);
                        accB = f4fma(w, x2, accB);
                    }
                    hE[p][tid] = make_float4(accA.x, accA.y, accB.x, accB.y);
                    hO[p][tid] = make_float4(accA.z, accA.w, accB.z, accB.w);
                    __syncthreads();
                    // ---- horizontal 11-tap conv (VALID: out[c] = sum x[c..c+10])
                    float4 o0 = make_float4(0.f, 0.f, 0.f, 0.f);    // col c0
                    float4 o1 = make_float4(0.f, 0.f, 0.f, 0.f);    // col c0+1
                    #pragma unroll
                    for (int m = 0; m < 6; ++m) {
                        float4 E = hE[p][tid + m];
                        float4 O = hO[p][tid + m];
                        float we = GW[2 * m];
                        o0 = f4fma(we, E, o0);
                        o1 = f4fma(we, O, o1);
                        if (m < 5)  o0 = f4fma(GW[2 * m + 1], O, o0);
                        if (m >= 1) o1 = f4fma(GW[2 * m - 1], E, o1);
                    }
                    if (c0 < OUTD) {
                        lsum += ssim_term(o0);
                        if (c0 + 1 < OUTD) lsum += ssim_term(o1);
                    }
                }
            }
        }
    }

    // block reduction: wave64 shuffle + LDS across 4 waves, one f64 atomic
    #pragma unroll
    for (int off = 32; off > 0; off >>= 1) lsum += __shfl_down(lsum, off);
    int wave = tid >> 6, lane = tid & 63;
    if (lane == 0) wave_sums[wave] = lsum;
    __syncthreads();
    if (tid == 0) {
        float s = wave_sums[0] + wave_sums[1] + wave_sums[2] + wave_sums[3];
        atomicAdd(accum, (double)s);
    }
}

__global__ void ssim_finalize(const double* __restrict__ accum, float* __restrict__ out)
{
    if (threadIdx.x == 0 && blockIdx.x == 0) {
        double mean = accum[0] / ((double)NPLANE * OUTD * OUTD);
        double l = 1.0 - mean;
        if (l < 0.0) l = 0.0;
        if (l > 1.0) l = 1.0;
        out[0] = (float)l;
    }
}

extern "C" void kernel_launch(void* const* d_in, const int* in_sizes, int n_in,
                              void* d_out, int out_size, void* d_ws, size_t ws_size,
                              hipStream_t stream)
{
    const float* input  = (const float*)d_in[0];   // [32,3,384,384]
    const float* target = (const float*)d_in[1];   // [32,3,512,512]
    float* out = (float*)d_out;
    double* accum = (double*)d_ws;

    hipMemsetAsync(accum, 0, sizeof(double), stream);

    dim3 grid(NCHUNK, NPLANE);
    ssim_stream<<<grid, dim3(256), 0, stream>>>(input, target, accum);
    ssim_finalize<<<1, 64, 0, stream>>>(accum, out);
}

// Round 7
// 260.569 us; speedup vs baseline: 1.1861x; 1.1558x over previous
//
#include <hip/hip_runtime.h>

// SSIM loss, streaming-row, vertical-conv-first, pair-processed (R7).
// input [32,3,384,384] --bilinear(align_corners)--> [512,512] vs target; 11x11 gaussian
// SSIM (VALID) -> mean over (96,502,502) -> loss = clip(1-mean,0,1).
//
// Per block: one plane x 32-output-row chunk; 256 threads x 2 cols.
// Region rows processed in PAIRS: stage rows r,r+1 into an 11-slot register ring of
// raw (s,d) (44 VGPRs, static indices), vertical 11-tap conv of (s,d,s^2,d^2) for the
// two completed output rows, write float4 to even/odd de-interleaved LDS (4 buffers,
// pair-parity alternated -> 1 barrier per pair), horizontal 11-tap conv + SSIM for both.
// launch_bounds(256,3): ~105 live regs fit the 170-reg budget -> no AGPRs, no spills.

constexpr int KS = 11;
constexpr int HI = 384, WI = 384, HO = 512, WO = 512;
constexpr int OUTD = 502;            // HO - KS + 1
constexpr int NPLANE = 96;
constexpr int CH_OUT = 32;
constexpr int NCHUNK = 16;
constexpr float C1 = 1.0e-4f;
constexpr float C2 = 9.0e-4f;

// gaussian(sigma=1.5, ks=11), normalized
__device__ __constant__ float GW[KS] = {
    0.00102838f, 0.00759876f, 0.03600076f, 0.10936070f, 0.21300554f,
    0.26601172f, 0.21300554f, 0.10936070f, 0.03600076f, 0.00759876f, 0.00102838f};

__device__ __forceinline__ float4 f4fma(float w, float4 x, float4 a)
{
    a.x = fmaf(w, x.x, a.x); a.y = fmaf(w, x.y, a.y);
    a.z = fmaf(w, x.z, a.z); a.w = fmaf(w, x.w, a.w);
    return a;
}

__device__ __forceinline__ float ssim_term(float4 f)
{
    float S = f.x, D = f.y, P = f.z, M = f.w;
    float SS = S * S, DD = D * D;
    float mu12 = 0.25f * (SS - DD);            // mu1*mu2
    float musq = 0.5f  * (SS + DD);            // mu1^2 + mu2^2
    float s12  = 0.25f * (P - M) - mu12;       // sigma12
    float ssum = 0.5f  * (P + M) - musq;       // sigma1 + sigma2
    float num = fmaf(2.f, mu12, C1) * fmaf(2.f, s12, C2);
    float den = (musq + C1) * (ssum + C2);
    return __fdividef(num, den);
}

__global__ __launch_bounds__(256, 3)
void ssim_stream(const float* __restrict__ input, const float* __restrict__ target,
                 double* __restrict__ accum)
{
    // vertical-conv outputs (S,D,P,M), even cols / odd cols, 4 buffers
    // (pair-member in bit0, pair-parity in bit1). Reads at [tid+0..5] -> 262 slots.
    __shared__ __align__(16) float4 hE[4][262];
    __shared__ __align__(16) float4 hO[4][262];
    __shared__ float wave_sums[4];

    const int tid   = threadIdx.x;
    const int chunk = blockIdx.x;
    const int plane = blockIdx.y;
    const int oyb   = chunk * CH_OUT;
    const int nout  = min(CH_OUT, OUTD - oyb);
    const int rows  = nout + KS - 1;          // 42 (full) or 32 (last) — always even

    const int c0 = 2 * tid;

    // x-geometry (align_corners): p = c*383/511 (f32-exact decision)
    float pA = (float)(c0 * (WI - 1)) / (float)(WO - 1);
    int   xA0 = (int)pA; float wxA = pA - (float)xA0;
    float pB = (float)((c0 + 1) * (WI - 1)) / (float)(WO - 1);
    int   xB0 = (int)pB; float wxB = pB - (float)xB0;
    const bool shift = (xB0 != xA0);
    const int xs0 = xA0, xs1 = min(xA0 + 1, WI - 1), xs2 = min(xA0 + 2, WI - 1);

    const float* __restrict__ ip = input  + (size_t)plane * HI * WI;
    const float* __restrict__ tp = target + (size_t)plane * HO * WO;

    // raw-input ring: slot = region_row % 11, (s0,d0,s1,d1)
    float4 q[11];

    // 2-deep preload pipeline, slot = row parity (static after unroll)
    float u0[2], u1[2], u2[2], v0[2], v1[2], v2[2], wyp[2];
    float2 tg[2];
    auto PRELOAD = [&](int r, int sl) {
        int y = oyb + r;                       // <= 511
        float py = (float)(y * (HI - 1)) / (float)(HO - 1);
        int y0 = (int)py; wyp[sl] = py - (float)y0;
        int y1 = min(y0 + 1, HI - 1);
        const float* r0 = ip + y0 * WI;
        const float* r1 = ip + y1 * WI;
        u0[sl] = r0[xs0]; u1[sl] = r0[xs1]; u2[sl] = r0[xs2];
        v0[sl] = r1[xs0]; v1[sl] = r1[xs1]; v2[sl] = r1[xs2];
        tg[sl] = *(const float2*)&tp[y * WO + c0];
    };
    // consume pipeline slot sl: bilinear -> (s,d) into ring slot im
    auto STAGE = [&](int im, int sl) {
        float wy = wyp[sl];
        float V0 = fmaf(wy, v0[sl] - u0[sl], u0[sl]);
        float V1 = fmaf(wy, v1[sl] - u1[sl], u1[sl]);
        float V2 = fmaf(wy, v2[sl] - u2[sl], u2[sl]);
        float a0 = fmaf(wxA, V1 - V0, V0);
        float bL = shift ? V1 : V0;
        float bR = shift ? V2 : V1;
        float a1 = fmaf(wxB, bR - bL, bL);
        float2 tv = tg[sl];
        q[im] = make_float4(a0 + tv.x, a0 - tv.x, a1 + tv.y, a1 - tv.y);
    };
    // vertical 11-tap conv for the output row whose last region row sits in ring
    // slot im; write (S,D,P,M) for both cols into buffer buf.
    auto VCONV = [&](int im, int buf) {
        float4 accA = make_float4(0.f, 0.f, 0.f, 0.f);  // (S0,D0,S1,D1)
        float4 accB = make_float4(0.f, 0.f, 0.f, 0.f);  // (P0,M0,P1,M1)
        #pragma unroll
        for (int j = 0; j < KS; ++j) {
            const int sl = (im + 1 + j) % 11;           // static
            float4 x = q[sl];
            float4 x2 = make_float4(x.x * x.x, x.y * x.y, x.z * x.z, x.w * x.w);
            float w = GW[j];
            accA = f4fma(w, x,  accA);
            accB = f4fma(w, x2, accB);
        }
        hE[buf][tid] = make_float4(accA.x, accA.y, accB.x, accB.y);
        hO[buf][tid] = make_float4(accA.z, accA.w, accB.z, accB.w);
    };

    float lsum = 0.f;
    // horizontal 11-tap conv + SSIM for both cols from buffer buf
    auto HCONV = [&](int buf) {
        float4 o0 = make_float4(0.f, 0.f, 0.f, 0.f);
        float4 o1 = make_float4(0.f, 0.f, 0.f, 0.f);
        #pragma unroll
        for (int m = 0; m < 6; ++m) {
            float4 E = hE[buf][tid + m];
            float4 O = hO[buf][tid + m];
            float we = GW[2 * m];
            o0 = f4fma(we, E, o0);
            o1 = f4fma(we, O, o1);
            if (m < 5)  o0 = f4fma(GW[2 * m + 1], O, o0);
            if (m >= 1) o1 = f4fma(GW[2 * m - 1], E, o1);
        }
        if (c0 < OUTD) {
            lsum += ssim_term(o0);
            if (c0 + 1 < OUTD) lsum += ssim_term(o1);
        }
    };

    PRELOAD(0, 0);
    PRELOAD(1, 1);

    for (int t = 0; t < 2; ++t) {
        #pragma unroll
        for (int ii = 0; ii < 22; ii += 2) {
            const int r = t * 22 + ii;                // even region row
            if (r < rows) {                           // uniform; rows even -> r+1<rows too
                const int imA = ii % 11;              // static; r%11
                const int imB = (ii + 1) % 11;        // static; (r+1)%11
                STAGE(imA, 0);
                STAGE(imB, 1);
                if (r + 2 < rows) PRELOAD(r + 2, 0);
                if (r + 3 < rows) PRELOAD(r + 3, 1);
                if (r >= KS - 1) {                    // output rows r-10, r-9 complete
                    const int bufb = (ii >> 1) & 1 ? 2 : 0;   // static pair parity
                    VCONV(imA, bufb + 0);
                    VCONV(imB, bufb + 1);
                    __syncthreads();
                    HCONV(bufb + 0);
                    HCONV(bufb + 1);
                }
            }
        }
    }

    // block reduction: wave64 shuffle + LDS across 4 waves, one f64 atomic
    #pragma unroll
    for (int off = 32; off > 0; off >>= 1) lsum += __shfl_down(lsum, off);
    int wave = tid >> 6, lane = tid & 63;
    if (lane == 0) wave_sums[wave] = lsum;
    __syncthreads();
    if (tid == 0) {
        float s = wave_sums[0] + wave_sums[1] + wave_sums[2] + wave_sums[3];
        atomicAdd(accum, (double)s);
    }
}

__global__ void ssim_finalize(const double* __restrict__ accum, float* __restrict__ out)
{
    if (threadIdx.x == 0 && blockIdx.x == 0) {
        double mean = accum[0] / ((double)NPLANE * OUTD * OUTD);
        double l = 1.0 - mean;
        if (l < 0.0) l = 0.0;
        if (l > 1.0) l = 1.0;
        out[0] = (float)l;
    }
}

extern "C" void kernel_launch(void* const* d_in, const int* in_sizes, int n_in,
                              void* d_out, int out_size, void* d_ws, size_t ws_size,
                              hipStream_t stream)
{
    const float* input  = (const float*)d_in[0];   // [32,3,384,384]
    const float* target = (const float*)d_in[1];   // [32,3,512,512]
    float* out = (float*)d_out;
    double* accum = (double*)d_ws;

    hipMemsetAsync(accum, 0, sizeof(double), stream);

    dim3 grid(NCHUNK, NPLANE);
    ssim_stream<<<grid, dim3(256), 0, stream>>>(input, target, accum);
    ssim_finalize<<<1, 64, 0, stream>>>(accum, out);
}